// Round 6
// baseline (1217.103 us; speedup 1.0000x reference)
//
#include <hip/hip_runtime.h>

typedef _Float16 f16;
typedef __attribute__((ext_vector_type(8))) _Float16 f16x8;
typedef __attribute__((ext_vector_type(4))) _Float16 f16x4;
typedef __attribute__((ext_vector_type(4))) float f32x4;

#define SLICE_H 4326400   // 33800 padded positions * 128 ch (elements)

// ---------------- helpers ----------------

__device__ __forceinline__ void gld_lds16(void* lds, const void* g) {
  // async global->LDS, 16B per lane; LDS dest = wave-uniform base + lane*16
  __builtin_amdgcn_global_load_lds(
      (const __attribute__((address_space(1))) void*)g,
      (__attribute__((address_space(3))) void*)lds, 16, 0, 0);
}

__device__ __forceinline__ float sigf(float v) { return 1.0f / (1.0f + __expf(-v)); }
__device__ __forceinline__ float tanh_fast(float v) { return 2.0f / (1.0f + __expf(-2.0f * v)) - 1.0f; }

// ---------------- weight transform: [O][I][3][3] -> [tap][O*I] f16 ----------------

__global__ __launch_bounds__(256) void kwt(const float* __restrict__ wsrc,
                                           f16* __restrict__ th, int R) {
  int idx = blockIdx.x * 256 + threadIdx.x;
  if (idx >= 9 * R) return;
  int tap = idx / R, r = idx - tap * R;     // r = cout*CIN + ci
  th[idx] = (f16)wsrc[(size_t)r * 9 + tap]; // src: (cout*CIN+ci)*9 + (dy*3+dx)
}

// ---------------- x slice: NCHW fp32 -> padded NHWC f16 ----------------

__global__ __launch_bounds__(256) void kxform(const float* __restrict__ xt,
                                              f16* __restrict__ xp) {
  int pid = blockIdx.x * 256 + threadIdx.x;          // 2*128*128 pixels
  int b = pid >> 14, y = (pid >> 7) & 127, x = pid & 127;
  const float* src = xt + (size_t)b * 64 * 16384 + (size_t)y * 128 + x;
  size_t doff = ((size_t)((b * 130 + y + 1) * 130 + (x + 1))) * 64;
#pragma unroll
  for (int cc = 0; cc < 8; ++cc) {
    f16x8 vh;
#pragma unroll
    for (int j = 0; j < 8; ++j) vh[j] = (f16)src[(size_t)(cc * 8 + j) * 16384];
    *(f16x8*)(xp + doff + cc * 8) = vh;
  }
}

// ---------------- gate conv: implicit GEMM M=32768 N=512 K=1728 ----------------
// block: one y-row of one image (128 px) x ALL 512 couts; 8 waves (2M x 4N),
// wave tile 64x128 (acc[4][8]).  Grid = 256 blocks = exactly 1/CU.
// LDS: A patch [3][132][32] (halo reuse over 9 taps) + B dbuf [2][512][32].
// XOR chunk-swizzle (key = row&3) on 16B slots, applied at stage via
// pre-swizzled global source (global_load_lds writes linearly) and at read.

#define SMEM_G (25344 + 65536)

__global__ __launch_bounds__(512, 2) void kgates(
    const f16* __restrict__ xp, const f16* __restrict__ hp,
    const f16* __restrict__ wg, f16* __restrict__ gates) {
  extern __shared__ char smem[];
  f16* Ap = (f16*)smem;                    // [3][132][32]
  f16* Bp = (f16*)(smem + 25344);          // [2][512][32]
  const int tid = threadIdx.x;
  const int lane = tid & 63;
  const int w = tid >> 6;
  const int y = blockIdx.x;
  const int b = blockIdx.y;
  const int wm = w >> 2, wn = w & 3;
  const int chunk = (lane & 3) ^ ((lane >> 2) & 3);   // pre-swizzled source chunk

  f32x4 acc[4][8] = {};

  auto stageA = [&](int cig) {
    const f16* S; int CS, cigl;
    if (cig < 2) { S = xp; CS = 64;  cigl = cig; }
    else         { S = hp; CS = 128; cigl = cig - 2; }
    for (int i = w; i < 27; i += 8) {
      int dy = i / 9, sub = i - dy * 9;
      int xp0 = sub * 16;
      const f16* src = S +
          ((size_t)((b * 130 + y + dy) * 130 + xp0 + (lane >> 2))) * CS +
          cigl * 32 + chunk * 8;
      f16* dst = Ap + (dy * 132 + xp0) * 32;
      if (sub == 8) { if (lane < 16) gld_lds16(dst, src); }
      else gld_lds16(dst, src);
    }
  };
  auto stageB = [&](int cig, int tap, int buf) {
    for (int i = w; i < 32; i += 8) {
      const f16* src = wg +
          ((size_t)(tap * 512 + i * 16 + (lane >> 2))) * 192 +
          cig * 32 + chunk * 8;
      gld_lds16(Bp + buf * 16384 + i * 512, src);
    }
  };

  stageA(0);
  stageB(0, 0, 0);
  __syncthreads();

  int pp = 0;
  for (int cig = 0; cig < 6; ++cig) {
    for (int tap = 0; tap < 9; ++tap) {
      if (tap < 8) stageB(cig, tap + 1, pp ^ 1);
      else if (cig < 5) stageB(cig + 1, 0, pp ^ 1);
      const int dy = tap / 3, dx = tap - dy * 3;
      const int q = lane >> 4;
      f16x8 af[4], bfr[8];
#pragma unroll
      for (int mf = 0; mf < 4; ++mf) {
        int r = wm * 64 + mf * 16 + (lane & 15) + dx;
        af[mf] = *(const f16x8*)(Ap + (dy * 132 + r) * 32 + ((q ^ (r & 3)) << 3));
      }
#pragma unroll
      for (int nf = 0; nf < 8; ++nf) {
        int n = wn * 128 + nf * 16 + (lane & 15);
        bfr[nf] = *(const f16x8*)(Bp + pp * 16384 + n * 32 + ((q ^ (lane & 3)) << 3));
      }
#pragma unroll
      for (int mf = 0; mf < 4; ++mf)
#pragma unroll
        for (int nf = 0; nf < 8; ++nf)
          acc[mf][nf] = __builtin_amdgcn_mfma_f32_16x16x32_f16(af[mf], bfr[nf], acc[mf][nf], 0, 0, 0);
      __syncthreads();
      pp ^= 1;
    }
    if (cig < 5) { stageA(cig + 1); __syncthreads(); }
  }

  // epilogue: D[row=(l>>4)*4+r][col=l&15] -> gates[pixel][cout] f16
  size_t pixbase = ((size_t)(b * 128 + y)) * 128;
#pragma unroll
  for (int mf = 0; mf < 4; ++mf) {
#pragma unroll
    for (int nf = 0; nf < 8; ++nf) {
      int cout = wn * 128 + nf * 16 + (lane & 15);
#pragma unroll
      for (int r = 0; r < 4; ++r) {
        int x = wm * 64 + mf * 16 + (lane >> 4) * 4 + r;
        gates[(pixbase + x) * 512 + cout] = (f16)acc[mf][nf][r];
      }
    }
  }
}

// ---------------- pointwise LSTM ----------------

__global__ __launch_bounds__(256) void kpoint(const f16* __restrict__ gates,
                                              const float* __restrict__ bg,
                                              float* __restrict__ cbuf,
                                              f16* __restrict__ hslot) {
  int gid = blockIdx.x * 256 + threadIdx.x;   // pixel*32 + cq
  int pixel = gid >> 5, cq = gid & 31;
  int b = pixel >> 14, y = (pixel >> 7) & 127, x = pixel & 127;
  size_t gb = (size_t)pixel * 512 + cq * 4;
  const f16x4 ig = *(const f16x4*)(gates + gb);
  const f16x4 fg = *(const f16x4*)(gates + gb + 128);
  const f16x4 og = *(const f16x4*)(gates + gb + 256);
  const f16x4 gg = *(const f16x4*)(gates + gb + 384);
  const f32x4 bi  = *(const f32x4*)(bg + cq * 4);
  const f32x4 bff = *(const f32x4*)(bg + cq * 4 + 128);
  const f32x4 boo = *(const f32x4*)(bg + cq * 4 + 256);
  const f32x4 bgg = *(const f32x4*)(bg + cq * 4 + 384);
  f32x4 co = *(const f32x4*)(cbuf + (size_t)pixel * 128 + cq * 4);
  f32x4 cn;
  f16x4 hh;
#pragma unroll
  for (int j = 0; j < 4; ++j) {
    float iv = sigf((float)ig[j] + bi[j]);
    float fv = sigf((float)fg[j] + bff[j]);
    float ov = sigf((float)og[j] + boo[j]);
    float gv = tanh_fast((float)gg[j] + bgg[j]);
    float cv = fv * co[j] + iv * gv;
    float hv = ov * tanh_fast(cv);
    cn[j] = cv;
    hh[j] = (f16)hv;
  }
  *(f32x4*)(cbuf + (size_t)pixel * 128 + cq * 4) = cn;
  size_t hoff = ((size_t)((b * 130 + y + 1) * 130 + (x + 1))) * 128 + cq * 4;
  *(f16x4*)(hslot + hoff) = hh;
}

// ---------------- output conv, batched over 4 timesteps: M=131072 N=64 K=1152 ----
// block: 128 px row x 64 couts; 4 waves M-split, wave tile 32x64 (acc[2][4]).

#define SMEM_O (25344 + 8192)

__global__ __launch_bounds__(256, 4) void koutconv(
    const f16* __restrict__ hr, int slot0, const f16* __restrict__ wo,
    const float* __restrict__ bo, float* __restrict__ outb) {
  extern __shared__ char smem[];
  f16* Ap = (f16*)smem;                    // [3][132][32]
  f16* Bp = (f16*)(smem + 25344);          // [2][64][32]
  const int tid = threadIdx.x, lane = tid & 63, w = tid >> 6;
  const int y = blockIdx.x;
  const int b = blockIdx.y;
  const int ts = blockIdx.z;
  const f16* hp = hr + (size_t)((slot0 + ts) % 5) * SLICE_H;
  float* outt = outb + (size_t)ts * 2 * 64 * 16384;
  const int chunk = (lane & 3) ^ ((lane >> 2) & 3);

  f32x4 acc[2][4] = {};

  auto stageA = [&](int cig) {
    for (int i = w; i < 27; i += 4) {
      int dy = i / 9, sub = i - dy * 9;
      int xp0 = sub * 16;
      const f16* src = hp +
          ((size_t)((b * 130 + y + dy) * 130 + xp0 + (lane >> 2))) * 128 +
          cig * 32 + chunk * 8;
      f16* dst = Ap + (dy * 132 + xp0) * 32;
      if (sub == 8) { if (lane < 16) gld_lds16(dst, src); }
      else gld_lds16(dst, src);
    }
  };
  auto stageB = [&](int cig, int tap, int buf) {
    const f16* src = wo +
        ((size_t)(tap * 64 + w * 16 + (lane >> 2))) * 128 +
        cig * 32 + chunk * 8;
    gld_lds16(Bp + buf * 2048 + w * 512, src);
  };

  stageA(0);
  stageB(0, 0, 0);
  __syncthreads();

  int pp = 0;
  for (int cig = 0; cig < 4; ++cig) {
    for (int tap = 0; tap < 9; ++tap) {
      if (tap < 8) stageB(cig, tap + 1, pp ^ 1);
      else if (cig < 3) stageB(cig + 1, 0, pp ^ 1);
      const int dy = tap / 3, dx = tap - dy * 3;
      const int q = lane >> 4;
      f16x8 af[2], bfr[4];
#pragma unroll
      for (int mf = 0; mf < 2; ++mf) {
        int r = w * 32 + mf * 16 + (lane & 15) + dx;
        af[mf] = *(const f16x8*)(Ap + (dy * 132 + r) * 32 + ((q ^ (r & 3)) << 3));
      }
#pragma unroll
      for (int nf = 0; nf < 4; ++nf) {
        int n = nf * 16 + (lane & 15);
        bfr[nf] = *(const f16x8*)(Bp + pp * 2048 + n * 32 + ((q ^ (lane & 3)) << 3));
      }
#pragma unroll
      for (int mf = 0; mf < 2; ++mf)
#pragma unroll
        for (int nf = 0; nf < 4; ++nf)
          acc[mf][nf] = __builtin_amdgcn_mfma_f32_16x16x32_f16(af[mf], bfr[nf], acc[mf][nf], 0, 0, 0);
      __syncthreads();
      pp ^= 1;
    }
    if (cig < 3) { stageA(cig + 1); __syncthreads(); }
  }

#pragma unroll
  for (int nf = 0; nf < 4; ++nf) {
    int cout = nf * 16 + (lane & 15);
    float bias = bo[cout];
#pragma unroll
    for (int mf = 0; mf < 2; ++mf) {
      int xbase = w * 32 + mf * 16 + (lane >> 4) * 4;
      f32x4 v = acc[mf][nf];
      v[0] += bias; v[1] += bias; v[2] += bias; v[3] += bias;
      *(f32x4*)(outt + (((size_t)b * 64 + cout) * 128 + y) * 128 + xbase) = v;
    }
  }
}

// ---------------- host ----------------

extern "C" void kernel_launch(void* const* d_in, const int* in_sizes, int n_in,
                              void* d_out, int out_size, void* d_ws, size_t ws_size,
                              hipStream_t stream) {
  const float* x  = (const float*)d_in[0];
  const float* Wg = (const float*)d_in[1];
  const float* bg = (const float*)d_in[2];
  const float* Wo = (const float*)d_in[3];
  const float* bo = (const float*)d_in[4];
  float* out = (float*)d_out;

  char* base = (char*)d_ws;
  size_t off = 0;
  auto carve = [&](size_t bytes) {
    char* p = base + off;
    off += (bytes + 1023) & ~(size_t)1023;
    return p;
  };
  const size_t PADPOS = (size_t)2 * 130 * 130;           // 33800 padded positions
  const size_t xpad_b  = PADPOS * 64 * 2 + 1024;          // f16
  const size_t hring_b = (size_t)5 * SLICE_H * 2 + 1024;  // 5 padded h slices, f16
  const size_t c_b = (size_t)2 * 128 * 128 * 128 * 4;     // fp32 cell state
  const size_t g_b = (size_t)2 * 128 * 128 * 512 * 2;     // f16 gates

  f16* xp    = (f16*)carve(xpad_b);
  f16* hr    = (f16*)carve(hring_b);
  float* cbuf = (float*)carve(c_b);
  f16* gates = (f16*)carve(g_b);
  f16* wg    = (f16*)carve((size_t)9 * 512 * 192 * 2);
  f16* wo    = (f16*)carve((size_t)9 * 64 * 128 * 2);

  // zero state + pad borders once (in-stream: graph-replay deterministic;
  // interiors are fully rewritten every use, borders stay zero)
  hipMemsetAsync(xp, 0, xpad_b, stream);
  hipMemsetAsync(hr, 0, hring_b, stream);
  hipMemsetAsync(cbuf, 0, c_b, stream);

  kwt<<<(9 * 512 * 192 + 255) / 256, 256, 0, stream>>>(Wg, wg, 512 * 192);
  kwt<<<(9 * 64 * 128 + 255) / 256, 256, 0, stream>>>(Wo, wo, 64 * 128);

  for (int t = 0; t < 12; ++t) {
    const float* xt = x + (size_t)t * 2 * 64 * 16384;
    kxform<<<128, 256, 0, stream>>>(xt, xp);
    kgates<<<dim3(128, 2), 512, SMEM_G, stream>>>(
        xp, hr + (size_t)(t % 5) * SLICE_H, wg, gates);
    kpoint<<<4096, 256, 0, stream>>>(gates, bg, cbuf,
        hr + (size_t)((t + 1) % 5) * SLICE_H);
    if ((t & 3) == 3) {
      koutconv<<<dim3(128, 2, 4), 256, SMEM_O, stream>>>(
          hr, (t - 2) % 5, wo, bo, out + (size_t)(t - 3) * 2 * 64 * 16384);
    }
  }
}

// Round 7
// 1144.276 us; speedup vs baseline: 1.0636x; 1.0636x over previous
//
#include <hip/hip_runtime.h>

typedef _Float16 f16;
typedef __attribute__((ext_vector_type(8))) _Float16 f16x8;
typedef __attribute__((ext_vector_type(4))) _Float16 f16x4;
typedef __attribute__((ext_vector_type(4))) float f32x4;

#define SLICE_H 4326400   // 33800 padded positions * 128 ch (elements)

// ---------------- helpers ----------------

__device__ __forceinline__ void gld_lds16(void* lds, const void* g) {
  // async global->LDS, 16B per lane; LDS dest = wave-uniform base + lane*16
  __builtin_amdgcn_global_load_lds(
      (const __attribute__((address_space(1))) void*)g,
      (__attribute__((address_space(3))) void*)lds, 16, 0, 0);
}

__device__ __forceinline__ float sigf(float v) { return 1.0f / (1.0f + __expf(-v)); }
__device__ __forceinline__ float tanh_fast(float v) { return 2.0f / (1.0f + __expf(-2.0f * v)) - 1.0f; }

// ---------------- weight transform: [O][I][3][3] -> [tap][O*I] f16 ----------------

__global__ __launch_bounds__(256) void kwt(const float* __restrict__ wsrc,
                                           f16* __restrict__ th, int R) {
  int idx = blockIdx.x * 256 + threadIdx.x;
  if (idx >= 9 * R) return;
  int tap = idx / R, r = idx - tap * R;     // r = cout*CIN + ci
  th[idx] = (f16)wsrc[(size_t)r * 9 + tap]; // src: (cout*CIN+ci)*9 + (dy*3+dx)
}

// ---------------- x slice: NCHW fp32 -> padded NHWC f16 ----------------

__global__ __launch_bounds__(256) void kxform(const float* __restrict__ xt,
                                              f16* __restrict__ xp) {
  int pid = blockIdx.x * 256 + threadIdx.x;          // 2*128*128 pixels
  int b = pid >> 14, y = (pid >> 7) & 127, x = pid & 127;
  const float* src = xt + (size_t)b * 64 * 16384 + (size_t)y * 128 + x;
  size_t doff = ((size_t)((b * 130 + y + 1) * 130 + (x + 1))) * 64;
#pragma unroll
  for (int cc = 0; cc < 8; ++cc) {
    f16x8 vh;
#pragma unroll
    for (int j = 0; j < 8; ++j) vh[j] = (f16)src[(size_t)(cc * 8 + j) * 16384];
    *(f16x8*)(xp + doff + cc * 8) = vh;
  }
}

// ---------------- gate conv: implicit GEMM M=32768 N=512 K=1728 ----------------
// block: one y-row of one image (128 px) x 256 couts (N split 2-way for
// 2 blocks/CU); 8 waves (2M x 4N), wave tile 64x64 (acc[4][4]).
// LDS: A patch [3][132][32] (halo reuse over 9 taps) + B dbuf [2][256][32]
// = 58112 B -> 2 blocks/CU.
// XOR chunk-swizzle on 16B slots, key = (row>>1)&3 (parity-correct: even
// rows cycle all 4 chunk slots -> 2-way max on ds_read_b128). Applied at
// stage via pre-swizzled global source (global_load_lds writes linearly)
// and re-applied at read.

#define SMEM_G (25344 + 32768)

__global__ __launch_bounds__(512, 4) void kgates(
    const f16* __restrict__ xp, const f16* __restrict__ hp,
    const f16* __restrict__ wg, f16* __restrict__ gates) {
  extern __shared__ char smem[];
  f16* Ap = (f16*)smem;                    // [3][132][32]
  f16* Bp = (f16*)(smem + 25344);          // [2][256][32]
  const int tid = threadIdx.x;
  const int lane = tid & 63;
  const int w = tid >> 6;
  const int y = blockIdx.x;
  const int b = blockIdx.y;
  const int n0 = blockIdx.z * 256;
  const int wm = w >> 2, wn = w & 3;
  // stage-side source chunk: LDS slot (lane&3) of row (16-aligned + lane>>2)
  // must hold global chunk (lane&3) ^ key(row), key(row) = (row>>1)&3
  const int chunk = (lane & 3) ^ ((lane >> 3) & 3);

  f32x4 acc[4][4] = {};

  auto stageA = [&](int cig) {
    const f16* S; int CS, cigl;
    if (cig < 2) { S = xp; CS = 64;  cigl = cig; }
    else         { S = hp; CS = 128; cigl = cig - 2; }
    for (int i = w; i < 27; i += 8) {
      int dy = i / 9, sub = i - dy * 9;
      int xp0 = sub * 16;
      const f16* src = S +
          ((size_t)((b * 130 + y + dy) * 130 + xp0 + (lane >> 2))) * CS +
          cigl * 32 + chunk * 8;
      f16* dst = Ap + (dy * 132 + xp0) * 32;
      if (sub == 8) { if (lane < 16) gld_lds16(dst, src); }
      else gld_lds16(dst, src);
    }
  };
  auto stageB = [&](int cig, int tap, int buf) {
    for (int i = w; i < 16; i += 8) {
      const f16* src = wg +
          ((size_t)(tap * 512 + n0 + i * 16 + (lane >> 2))) * 192 +
          cig * 32 + chunk * 8;
      gld_lds16(Bp + buf * 8192 + i * 512, src);
    }
  };

  stageA(0);
  stageB(0, 0, 0);
  __syncthreads();

  int pp = 0;
  for (int cig = 0; cig < 6; ++cig) {
    for (int tap = 0; tap < 9; ++tap) {
      if (tap < 8) stageB(cig, tap + 1, pp ^ 1);
      else if (cig < 5) stageB(cig + 1, 0, pp ^ 1);
      const int dy = tap / 3, dx = tap - dy * 3;
      const int q = lane >> 4;
      f16x8 af[4], bfr[4];
#pragma unroll
      for (int mf = 0; mf < 4; ++mf) {
        int r = wm * 64 + mf * 16 + (lane & 15) + dx;
        af[mf] = *(const f16x8*)(Ap + (dy * 132 + r) * 32 + ((q ^ ((r >> 1) & 3)) << 3));
      }
#pragma unroll
      for (int nf = 0; nf < 4; ++nf) {
        int n = wn * 64 + nf * 16 + (lane & 15);
        bfr[nf] = *(const f16x8*)(Bp + pp * 8192 + n * 32 + ((q ^ ((n >> 1) & 3)) << 3));
      }
#pragma unroll
      for (int mf = 0; mf < 4; ++mf)
#pragma unroll
        for (int nf = 0; nf < 4; ++nf)
          acc[mf][nf] = __builtin_amdgcn_mfma_f32_16x16x32_f16(af[mf], bfr[nf], acc[mf][nf], 0, 0, 0);
      __syncthreads();
      pp ^= 1;
    }
    if (cig < 5) { stageA(cig + 1); __syncthreads(); }
  }

  // epilogue: D[row=(l>>4)*4+r][col=l&15] -> gates[pixel][cout] f16
  size_t pixbase = ((size_t)(b * 128 + y)) * 128;
#pragma unroll
  for (int mf = 0; mf < 4; ++mf) {
#pragma unroll
    for (int nf = 0; nf < 4; ++nf) {
      int cout = n0 + wn * 64 + nf * 16 + (lane & 15);
#pragma unroll
      for (int r = 0; r < 4; ++r) {
        int x = wm * 64 + mf * 16 + (lane >> 4) * 4 + r;
        gates[(pixbase + x) * 512 + cout] = (f16)acc[mf][nf][r];
      }
    }
  }
}

// ---------------- pointwise LSTM ----------------

__global__ __launch_bounds__(256) void kpoint(const f16* __restrict__ gates,
                                              const float* __restrict__ bg,
                                              float* __restrict__ cbuf,
                                              f16* __restrict__ hslot) {
  int gid = blockIdx.x * 256 + threadIdx.x;   // pixel*32 + cq
  int pixel = gid >> 5, cq = gid & 31;
  int b = pixel >> 14, y = (pixel >> 7) & 127, x = pixel & 127;
  size_t gb = (size_t)pixel * 512 + cq * 4;
  const f16x4 ig = *(const f16x4*)(gates + gb);
  const f16x4 fg = *(const f16x4*)(gates + gb + 128);
  const f16x4 og = *(const f16x4*)(gates + gb + 256);
  const f16x4 gg = *(const f16x4*)(gates + gb + 384);
  const f32x4 bi  = *(const f32x4*)(bg + cq * 4);
  const f32x4 bff = *(const f32x4*)(bg + cq * 4 + 128);
  const f32x4 boo = *(const f32x4*)(bg + cq * 4 + 256);
  const f32x4 bgg = *(const f32x4*)(bg + cq * 4 + 384);
  f32x4 co = *(const f32x4*)(cbuf + (size_t)pixel * 128 + cq * 4);
  f32x4 cn;
  f16x4 hh;
#pragma unroll
  for (int j = 0; j < 4; ++j) {
    float iv = sigf((float)ig[j] + bi[j]);
    float fv = sigf((float)fg[j] + bff[j]);
    float ov = sigf((float)og[j] + boo[j]);
    float gv = tanh_fast((float)gg[j] + bgg[j]);
    float cv = fv * co[j] + iv * gv;
    float hv = ov * tanh_fast(cv);
    cn[j] = cv;
    hh[j] = (f16)hv;
  }
  *(f32x4*)(cbuf + (size_t)pixel * 128 + cq * 4) = cn;
  size_t hoff = ((size_t)((b * 130 + y + 1) * 130 + (x + 1))) * 128 + cq * 4;
  *(f16x4*)(hslot + hoff) = hh;
}

// ---------------- output conv, batched over 4 timesteps: M=131072 N=64 K=1152 ----
// block: 128 px row x 64 couts; 4 waves M-split, wave tile 32x64 (acc[2][4]).

#define SMEM_O (25344 + 8192)

__global__ __launch_bounds__(256, 4) void koutconv(
    const f16* __restrict__ hr, int slot0, const f16* __restrict__ wo,
    const float* __restrict__ bo, float* __restrict__ outb) {
  extern __shared__ char smem[];
  f16* Ap = (f16*)smem;                    // [3][132][32]
  f16* Bp = (f16*)(smem + 25344);          // [2][64][32]
  const int tid = threadIdx.x, lane = tid & 63, w = tid >> 6;
  const int y = blockIdx.x;
  const int b = blockIdx.y;
  const int ts = blockIdx.z;
  const f16* hp = hr + (size_t)((slot0 + ts) % 5) * SLICE_H;
  float* outt = outb + (size_t)ts * 2 * 64 * 16384;
  const int chunk = (lane & 3) ^ ((lane >> 3) & 3);

  f32x4 acc[2][4] = {};

  auto stageA = [&](int cig) {
    for (int i = w; i < 27; i += 4) {
      int dy = i / 9, sub = i - dy * 9;
      int xp0 = sub * 16;
      const f16* src = hp +
          ((size_t)((b * 130 + y + dy) * 130 + xp0 + (lane >> 2))) * 128 +
          cig * 32 + chunk * 8;
      f16* dst = Ap + (dy * 132 + xp0) * 32;
      if (sub == 8) { if (lane < 16) gld_lds16(dst, src); }
      else gld_lds16(dst, src);
    }
  };
  auto stageB = [&](int cig, int tap, int buf) {
    const f16* src = wo +
        ((size_t)(tap * 64 + w * 16 + (lane >> 2))) * 128 +
        cig * 32 + chunk * 8;
    gld_lds16(Bp + buf * 2048 + w * 512, src);
  };

  stageA(0);
  stageB(0, 0, 0);
  __syncthreads();

  int pp = 0;
  for (int cig = 0; cig < 4; ++cig) {
    for (int tap = 0; tap < 9; ++tap) {
      if (tap < 8) stageB(cig, tap + 1, pp ^ 1);
      else if (cig < 3) stageB(cig + 1, 0, pp ^ 1);
      const int dy = tap / 3, dx = tap - dy * 3;
      const int q = lane >> 4;
      f16x8 af[2], bfr[4];
#pragma unroll
      for (int mf = 0; mf < 2; ++mf) {
        int r = w * 32 + mf * 16 + (lane & 15) + dx;
        af[mf] = *(const f16x8*)(Ap + (dy * 132 + r) * 32 + ((q ^ ((r >> 1) & 3)) << 3));
      }
#pragma unroll
      for (int nf = 0; nf < 4; ++nf) {
        int n = nf * 16 + (lane & 15);
        bfr[nf] = *(const f16x8*)(Bp + pp * 2048 + n * 32 + ((q ^ ((n >> 1) & 3)) << 3));
      }
#pragma unroll
      for (int mf = 0; mf < 2; ++mf)
#pragma unroll
        for (int nf = 0; nf < 4; ++nf)
          acc[mf][nf] = __builtin_amdgcn_mfma_f32_16x16x32_f16(af[mf], bfr[nf], acc[mf][nf], 0, 0, 0);
      __syncthreads();
      pp ^= 1;
    }
    if (cig < 3) { stageA(cig + 1); __syncthreads(); }
  }

#pragma unroll
  for (int nf = 0; nf < 4; ++nf) {
    int cout = nf * 16 + (lane & 15);
    float bias = bo[cout];
#pragma unroll
    for (int mf = 0; mf < 2; ++mf) {
      int xbase = w * 32 + mf * 16 + (lane >> 4) * 4;
      f32x4 v = acc[mf][nf];
      v[0] += bias; v[1] += bias; v[2] += bias; v[3] += bias;
      *(f32x4*)(outt + (((size_t)b * 64 + cout) * 128 + y) * 128 + xbase) = v;
    }
  }
}

// ---------------- host ----------------

extern "C" void kernel_launch(void* const* d_in, const int* in_sizes, int n_in,
                              void* d_out, int out_size, void* d_ws, size_t ws_size,
                              hipStream_t stream) {
  const float* x  = (const float*)d_in[0];
  const float* Wg = (const float*)d_in[1];
  const float* bg = (const float*)d_in[2];
  const float* Wo = (const float*)d_in[3];
  const float* bo = (const float*)d_in[4];
  float* out = (float*)d_out;

  char* base = (char*)d_ws;
  size_t off = 0;
  auto carve = [&](size_t bytes) {
    char* p = base + off;
    off += (bytes + 1023) & ~(size_t)1023;
    return p;
  };
  const size_t PADPOS = (size_t)2 * 130 * 130;           // 33800 padded positions
  const size_t xpad_b  = PADPOS * 64 * 2 + 1024;          // f16
  const size_t hring_b = (size_t)5 * SLICE_H * 2 + 1024;  // 5 padded h slices, f16
  const size_t c_b = (size_t)2 * 128 * 128 * 128 * 4;     // fp32 cell state
  const size_t g_b = (size_t)2 * 128 * 128 * 512 * 2;     // f16 gates

  f16* xp    = (f16*)carve(xpad_b);
  f16* hr    = (f16*)carve(hring_b);
  float* cbuf = (float*)carve(c_b);
  f16* gates = (f16*)carve(g_b);
  f16* wg    = (f16*)carve((size_t)9 * 512 * 192 * 2);
  f16* wo    = (f16*)carve((size_t)9 * 64 * 128 * 2);

  // zero state + pad borders once (in-stream: graph-replay deterministic;
  // interiors are fully rewritten every use, borders stay zero)
  hipMemsetAsync(xp, 0, xpad_b, stream);
  hipMemsetAsync(hr, 0, hring_b, stream);
  hipMemsetAsync(cbuf, 0, c_b, stream);

  kwt<<<(9 * 512 * 192 + 255) / 256, 256, 0, stream>>>(Wg, wg, 512 * 192);
  kwt<<<(9 * 64 * 128 + 255) / 256, 256, 0, stream>>>(Wo, wo, 64 * 128);

  for (int t = 0; t < 12; ++t) {
    const float* xt = x + (size_t)t * 2 * 64 * 16384;
    kxform<<<128, 256, 0, stream>>>(xt, xp);
    kgates<<<dim3(128, 2, 2), 512, SMEM_G, stream>>>(
        xp, hr + (size_t)(t % 5) * SLICE_H, wg, gates);
    kpoint<<<4096, 256, 0, stream>>>(gates, bg, cbuf,
        hr + (size_t)((t + 1) % 5) * SLICE_H);
    if ((t & 3) == 3) {
      koutconv<<<dim3(128, 2, 4), 256, SMEM_O, stream>>>(
          hr, (t - 2) % 5, wo, bo, out + (size_t)(t - 3) * 2 * 64 * 16384);
    }
  }
}

// Round 8
// 1134.008 us; speedup vs baseline: 1.0733x; 1.0091x over previous
//
#include <hip/hip_runtime.h>

typedef _Float16 f16;
typedef __attribute__((ext_vector_type(8))) _Float16 f16x8;
typedef __attribute__((ext_vector_type(4))) _Float16 f16x4;
typedef __attribute__((ext_vector_type(4))) float f32x4;

#define SLICE_H 4326400   // 33800 padded positions * 128 ch (elements)

// ---------------- helpers ----------------

__device__ __forceinline__ void gld_lds16(void* lds, const void* g) {
  // async global->LDS, 16B per lane; LDS dest = wave-uniform base + lane*16
  __builtin_amdgcn_global_load_lds(
      (const __attribute__((address_space(1))) void*)g,
      (__attribute__((address_space(3))) void*)lds, 16, 0, 0);
}

__device__ __forceinline__ float sigf(float v) { return 1.0f / (1.0f + __expf(-v)); }
__device__ __forceinline__ float tanh_fast(float v) { return 2.0f / (1.0f + __expf(-2.0f * v)) - 1.0f; }

// ---------------- weight transform: [O][I][3][3] -> [tap][O*I] f16 ----------------

__global__ __launch_bounds__(256) void kwt(const float* __restrict__ wsrc,
                                           f16* __restrict__ th, int R) {
  int idx = blockIdx.x * 256 + threadIdx.x;
  if (idx >= 9 * R) return;
  int tap = idx / R, r = idx - tap * R;     // r = cout*CIN + ci
  th[idx] = (f16)wsrc[(size_t)r * 9 + tap]; // src: (cout*CIN+ci)*9 + (dy*3+dx)
}

// ---------------- x slice: NCHW fp32 -> padded NHWC f16 ----------------

__global__ __launch_bounds__(256) void kxform(const float* __restrict__ xt,
                                              f16* __restrict__ xp) {
  int pid = blockIdx.x * 256 + threadIdx.x;          // 2*128*128 pixels
  int b = pid >> 14, y = (pid >> 7) & 127, x = pid & 127;
  const float* src = xt + (size_t)b * 64 * 16384 + (size_t)y * 128 + x;
  size_t doff = ((size_t)((b * 130 + y + 1) * 130 + (x + 1))) * 64;
#pragma unroll
  for (int cc = 0; cc < 8; ++cc) {
    f16x8 vh;
#pragma unroll
    for (int j = 0; j < 8; ++j) vh[j] = (f16)src[(size_t)(cc * 8 + j) * 16384];
    *(f16x8*)(xp + doff + cc * 8) = vh;
  }
}

// ---------------- gate conv: implicit GEMM M=32768 N=512 K=1728 ----------------
// block: one y-row of one image (128 px) x 256 couts; 8 waves (2M x 4N),
// wave tile 64x64 (acc[4][4]).  Counted-vmcnt pipeline (T3+T4):
// B prefetched 2 taps ahead into a 3-slot LDS ring; per-tap sync is
// {s_waitcnt vmcnt(2); s_barrier} -- never drain to 0 except at the 6
// cig boundaries (A-patch restage).  T5 setprio around the MFMA cluster.
// XOR chunk-swizzle key=(row>>1)&3, staged via pre-swizzled global source.

#define SMEM_G (25344 + 49152)

__global__ __launch_bounds__(512, 4) void kgates(
    const f16* __restrict__ xp, const f16* __restrict__ hp,
    const f16* __restrict__ wg, f16* __restrict__ gates) {
  extern __shared__ char smem[];
  f16* Ap = (f16*)smem;                    // [3][132][32]
  f16* Br = (f16*)(smem + 25344);          // ring [3][256][32]
  const int tid = threadIdx.x;
  const int lane = tid & 63;
  const int w = tid >> 6;
  const int y = blockIdx.x;
  const int b = blockIdx.y;
  const int n0 = blockIdx.z * 256;
  const int wm = w >> 2, wn = w & 3;
  const int chunk = (lane & 3) ^ ((lane >> 3) & 3);

  f32x4 acc[4][4] = {};

  auto stageA = [&](int cig) {
    const f16* S; int CS, cigl;
    if (cig < 2) { S = xp; CS = 64;  cigl = cig; }
    else         { S = hp; CS = 128; cigl = cig - 2; }
    for (int i = w; i < 27; i += 8) {
      int dy = i / 9, sub = i - dy * 9;
      int xp0 = sub * 16;
      const f16* src = S +
          ((size_t)((b * 130 + y + dy) * 130 + xp0 + (lane >> 2))) * CS +
          cigl * 32 + chunk * 8;
      f16* dst = Ap + (dy * 132 + xp0) * 32;
      if (sub == 8) { if (lane < 16) gld_lds16(dst, src); }
      else gld_lds16(dst, src);
    }
  };
  auto stageB = [&](int j) {               // j = global iter (cig*9+tap), 2/wave
    int cig = j / 9, tap = j - cig * 9;
    f16* dst = Br + (j % 3) * 8192;
    for (int i = w; i < 16; i += 8) {
      const f16* src = wg +
          ((size_t)(tap * 512 + n0 + i * 16 + (lane >> 2))) * 192 +
          cig * 32 + chunk * 8;
      gld_lds16(dst + i * 512, src);
    }
  };

  // prologue: A(0) + B(0) + B(1); keep newest 2 (B1) in flight
  stageA(0);
  stageB(0);
  stageB(1);
  asm volatile("s_waitcnt vmcnt(2)" ::: "memory");
  __builtin_amdgcn_s_barrier();

  for (int j = 0; j < 54; ++j) {
    const int cig = j / 9, tap = j - cig * 9;
    const int dy = tap / 3, dx = tap - dy * 3;
    const int q = lane >> 4;
    const f16* Bc = Br + (j % 3) * 8192;
    f16x8 af[4], bfr[4];
#pragma unroll
    for (int mf = 0; mf < 4; ++mf) {
      int r = wm * 64 + mf * 16 + (lane & 15) + dx;
      af[mf] = *(const f16x8*)(Ap + (dy * 132 + r) * 32 + ((q ^ ((r >> 1) & 3)) << 3));
    }
#pragma unroll
    for (int nf = 0; nf < 4; ++nf) {
      int n = wn * 64 + nf * 16 + (lane & 15);
      bfr[nf] = *(const f16x8*)(Bc + n * 32 + ((q ^ ((n >> 1) & 3)) << 3));
    }
    if (j + 2 < 54) stageB(j + 2);   // ring slot (j+2)%3: consumed at j-1, free
    __builtin_amdgcn_s_setprio(1);
#pragma unroll
    for (int mf = 0; mf < 4; ++mf)
#pragma unroll
      for (int nf = 0; nf < 4; ++nf)
        acc[mf][nf] = __builtin_amdgcn_mfma_f32_16x16x32_f16(af[mf], bfr[nf], acc[mf][nf], 0, 0, 0);
    __builtin_amdgcn_s_setprio(0);
    if (tap == 8) {
      // all waves done reading Ap (frag ds_reads completed pre-MFMA)
      __builtin_amdgcn_s_barrier();
      if (cig < 5) stageA(cig + 1);
      asm volatile("s_waitcnt vmcnt(0)" ::: "memory");
      __builtin_amdgcn_s_barrier();
    } else {
      if (j + 2 < 54) asm volatile("s_waitcnt vmcnt(2)" ::: "memory");
      else            asm volatile("s_waitcnt vmcnt(0)" ::: "memory");
      __builtin_amdgcn_s_barrier();
    }
  }

  // epilogue: D[row=(l>>4)*4+r][col=l&15] -> gates[pixel][cout] f16
  size_t pixbase = ((size_t)(b * 128 + y)) * 128;
#pragma unroll
  for (int mf = 0; mf < 4; ++mf) {
#pragma unroll
    for (int nf = 0; nf < 4; ++nf) {
      int cout = n0 + wn * 64 + nf * 16 + (lane & 15);
#pragma unroll
      for (int r = 0; r < 4; ++r) {
        int x = wm * 64 + mf * 16 + (lane >> 4) * 4 + r;
        gates[(pixbase + x) * 512 + cout] = (f16)acc[mf][nf][r];
      }
    }
  }
}

// ---------------- pointwise LSTM ----------------

__global__ __launch_bounds__(256) void kpoint(const f16* __restrict__ gates,
                                              const float* __restrict__ bg,
                                              float* __restrict__ cbuf,
                                              f16* __restrict__ hslot) {
  int gid = blockIdx.x * 256 + threadIdx.x;   // pixel*32 + cq
  int pixel = gid >> 5, cq = gid & 31;
  int b = pixel >> 14, y = (pixel >> 7) & 127, x = pixel & 127;
  size_t gb = (size_t)pixel * 512 + cq * 4;
  const f16x4 ig = *(const f16x4*)(gates + gb);
  const f16x4 fg = *(const f16x4*)(gates + gb + 128);
  const f16x4 og = *(const f16x4*)(gates + gb + 256);
  const f16x4 gg = *(const f16x4*)(gates + gb + 384);
  const f32x4 bi  = *(const f32x4*)(bg + cq * 4);
  const f32x4 bff = *(const f32x4*)(bg + cq * 4 + 128);
  const f32x4 boo = *(const f32x4*)(bg + cq * 4 + 256);
  const f32x4 bgg = *(const f32x4*)(bg + cq * 4 + 384);
  f32x4 co = *(const f32x4*)(cbuf + (size_t)pixel * 128 + cq * 4);
  f32x4 cn;
  f16x4 hh;
#pragma unroll
  for (int j = 0; j < 4; ++j) {
    float iv = sigf((float)ig[j] + bi[j]);
    float fv = sigf((float)fg[j] + bff[j]);
    float ov = sigf((float)og[j] + boo[j]);
    float gv = tanh_fast((float)gg[j] + bgg[j]);
    float cv = fv * co[j] + iv * gv;
    float hv = ov * tanh_fast(cv);
    cn[j] = cv;
    hh[j] = (f16)hv;
  }
  *(f32x4*)(cbuf + (size_t)pixel * 128 + cq * 4) = cn;
  size_t hoff = ((size_t)((b * 130 + y + 1) * 130 + (x + 1))) * 128 + cq * 4;
  *(f16x4*)(hslot + hoff) = hh;
}

// ---------------- output conv, batched over 4 timesteps: M=131072 N=64 K=1152 ----
// block: 128 px row x 64 couts; 4 waves M-split, wave tile 32x64 (acc[2][4]).
// Same counted-vmcnt ring-3 pipeline; steady-state wait vmcnt(1).

#define SMEM_O (25344 + 12288)

__global__ __launch_bounds__(256, 4) void koutconv(
    const f16* __restrict__ hr, int slot0, const f16* __restrict__ wo,
    const float* __restrict__ bo, float* __restrict__ outb) {
  extern __shared__ char smem[];
  f16* Ap = (f16*)smem;                    // [3][132][32]
  f16* Br = (f16*)(smem + 25344);          // ring [3][64][32]
  const int tid = threadIdx.x, lane = tid & 63, w = tid >> 6;
  const int y = blockIdx.x;
  const int b = blockIdx.y;
  const int ts = blockIdx.z;
  const f16* hp = hr + (size_t)((slot0 + ts) % 5) * SLICE_H;
  float* outt = outb + (size_t)ts * 2 * 64 * 16384;
  const int chunk = (lane & 3) ^ ((lane >> 3) & 3);

  f32x4 acc[2][4] = {};

  auto stageA = [&](int cig) {
    for (int i = w; i < 27; i += 4) {
      int dy = i / 9, sub = i - dy * 9;
      int xp0 = sub * 16;
      const f16* src = hp +
          ((size_t)((b * 130 + y + dy) * 130 + xp0 + (lane >> 2))) * 128 +
          cig * 32 + chunk * 8;
      f16* dst = Ap + (dy * 132 + xp0) * 32;
      if (sub == 8) { if (lane < 16) gld_lds16(dst, src); }
      else gld_lds16(dst, src);
    }
  };
  auto stageB = [&](int j) {               // 1 load/wave
    int cig = j / 9, tap = j - cig * 9;
    const f16* src = wo +
        ((size_t)(tap * 64 + w * 16 + (lane >> 2))) * 128 +
        cig * 32 + chunk * 8;
    gld_lds16(Br + (j % 3) * 2048 + w * 512, src);
  };

  stageA(0);
  stageB(0);
  stageB(1);
  asm volatile("s_waitcnt vmcnt(1)" ::: "memory");
  __builtin_amdgcn_s_barrier();

  for (int j = 0; j < 36; ++j) {
    const int cig = j / 9, tap = j - cig * 9;
    const int dy = tap / 3, dx = tap - dy * 3;
    const int q = lane >> 4;
    const f16* Bc = Br + (j % 3) * 2048;
    f16x8 af[2], bfr[4];
#pragma unroll
    for (int mf = 0; mf < 2; ++mf) {
      int r = w * 32 + mf * 16 + (lane & 15) + dx;
      af[mf] = *(const f16x8*)(Ap + (dy * 132 + r) * 32 + ((q ^ ((r >> 1) & 3)) << 3));
    }
#pragma unroll
    for (int nf = 0; nf < 4; ++nf) {
      int n = nf * 16 + (lane & 15);
      bfr[nf] = *(const f16x8*)(Bc + n * 32 + ((q ^ ((n >> 1) & 3)) << 3));
    }
    if (j + 2 < 36) stageB(j + 2);
    __builtin_amdgcn_s_setprio(1);
#pragma unroll
    for (int mf = 0; mf < 2; ++mf)
#pragma unroll
      for (int nf = 0; nf < 4; ++nf)
        acc[mf][nf] = __builtin_amdgcn_mfma_f32_16x16x32_f16(af[mf], bfr[nf], acc[mf][nf], 0, 0, 0);
    __builtin_amdgcn_s_setprio(0);
    if (tap == 8) {
      __builtin_amdgcn_s_barrier();
      if (cig < 3) stageA(cig + 1);
      asm volatile("s_waitcnt vmcnt(0)" ::: "memory");
      __builtin_amdgcn_s_barrier();
    } else {
      if (j + 2 < 36) asm volatile("s_waitcnt vmcnt(1)" ::: "memory");
      else            asm volatile("s_waitcnt vmcnt(0)" ::: "memory");
      __builtin_amdgcn_s_barrier();
    }
  }

#pragma unroll
  for (int nf = 0; nf < 4; ++nf) {
    int cout = nf * 16 + (lane & 15);
    float bias = bo[cout];
#pragma unroll
    for (int mf = 0; mf < 2; ++mf) {
      int xbase = w * 32 + mf * 16 + (lane >> 4) * 4;
      f32x4 v = acc[mf][nf];
      v[0] += bias; v[1] += bias; v[2] += bias; v[3] += bias;
      *(f32x4*)(outt + (((size_t)b * 64 + cout) * 128 + y) * 128 + xbase) = v;
    }
  }
}

// ---------------- host ----------------

extern "C" void kernel_launch(void* const* d_in, const int* in_sizes, int n_in,
                              void* d_out, int out_size, void* d_ws, size_t ws_size,
                              hipStream_t stream) {
  const float* x  = (const float*)d_in[0];
  const float* Wg = (const float*)d_in[1];
  const float* bg = (const float*)d_in[2];
  const float* Wo = (const float*)d_in[3];
  const float* bo = (const float*)d_in[4];
  float* out = (float*)d_out;

  char* base = (char*)d_ws;
  size_t off = 0;
  auto carve = [&](size_t bytes) {
    char* p = base + off;
    off += (bytes + 1023) & ~(size_t)1023;
    return p;
  };
  const size_t PADPOS = (size_t)2 * 130 * 130;           // 33800 padded positions
  const size_t xpad_b  = PADPOS * 64 * 2 + 1024;          // f16
  const size_t hring_b = (size_t)5 * SLICE_H * 2 + 1024;  // 5 padded h slices, f16
  const size_t c_b = (size_t)2 * 128 * 128 * 128 * 4;     // fp32 cell state
  const size_t g_b = (size_t)2 * 128 * 128 * 512 * 2;     // f16 gates

  f16* xp    = (f16*)carve(xpad_b);
  f16* hr    = (f16*)carve(hring_b);
  float* cbuf = (float*)carve(c_b);
  f16* gates = (f16*)carve(g_b);
  f16* wg    = (f16*)carve((size_t)9 * 512 * 192 * 2);
  f16* wo    = (f16*)carve((size_t)9 * 64 * 128 * 2);

  // zero state + pad borders once (in-stream: graph-replay deterministic;
  // interiors are fully rewritten every use, borders stay zero)
  hipMemsetAsync(xp, 0, xpad_b, stream);
  hipMemsetAsync(hr, 0, hring_b, stream);
  hipMemsetAsync(cbuf, 0, c_b, stream);

  kwt<<<(9 * 512 * 192 + 255) / 256, 256, 0, stream>>>(Wg, wg, 512 * 192);
  kwt<<<(9 * 64 * 128 + 255) / 256, 256, 0, stream>>>(Wo, wo, 64 * 128);

  for (int t = 0; t < 12; ++t) {
    const float* xt = x + (size_t)t * 2 * 64 * 16384;
    kxform<<<128, 256, 0, stream>>>(xt, xp);
    kgates<<<dim3(128, 2, 2), 512, SMEM_G, stream>>>(
        xp, hr + (size_t)(t % 5) * SLICE_H, wg, gates);
    kpoint<<<4096, 256, 0, stream>>>(gates, bg, cbuf,
        hr + (size_t)((t + 1) % 5) * SLICE_H);
    if ((t & 3) == 3) {
      koutconv<<<dim3(128, 2, 4), 256, SMEM_O, stream>>>(
          hr, (t - 2) % 5, wo, bo, out + (size_t)(t - 3) * 2 * 64 * 16384);
    }
  }
}

// Round 9
// 1031.593 us; speedup vs baseline: 1.1798x; 1.0993x over previous
//
#include <hip/hip_runtime.h>

typedef _Float16 f16;
typedef __attribute__((ext_vector_type(8))) _Float16 f16x8;
typedef __attribute__((ext_vector_type(4))) _Float16 f16x4;
typedef __attribute__((ext_vector_type(4))) float f32x4;

#define SLICE_H 4326400   // 33800 padded positions * 128 ch (elements)

// ---------------- helpers ----------------

__device__ __forceinline__ void gld_lds16(void* lds, const void* g) {
  // async global->LDS, 16B per lane; LDS dest = wave-uniform base + lane*16
  __builtin_amdgcn_global_load_lds(
      (const __attribute__((address_space(1))) void*)g,
      (__attribute__((address_space(3))) void*)lds, 16, 0, 0);
}

__device__ __forceinline__ float sigf(float v) { return 1.0f / (1.0f + __expf(-v)); }
__device__ __forceinline__ float tanh_fast(float v) { return 2.0f / (1.0f + __expf(-2.0f * v)) - 1.0f; }

// ---------------- weight transforms ----------------

// output-conv weights: [O][I][3][3] -> [tap][O*I] f16 (no permutation)
__global__ __launch_bounds__(256) void kwt(const float* __restrict__ wsrc,
                                           f16* __restrict__ th, int R) {
  int idx = blockIdx.x * 256 + threadIdx.x;
  if (idx >= 9 * R) return;
  int tap = idx / R, r = idx - tap * R;     // r = cout*CIN + ci
  th[idx] = (f16)wsrc[(size_t)r * 9 + tap];
}

// gate weights with gate-interleaved cout permutation:
//   original cout co = gate*128 + hch  (gate: i,f,o,g)
//   new row N = (hch>>6)*256 + ((hch&63)>>4)*64 + gate*16 + (hch&15)
// so that within a block (z = hch>>6), wave w (lch-high = w), MFMA frag nf
// == gate, lane&15 == lch low bits: the 4 gates of one (px,lch) land in one
// thread's acc[mf][0..3][r] -> LSTM computed fully in registers.
__global__ __launch_bounds__(256) void kwtg(const float* __restrict__ wsrc,
                                            f16* __restrict__ th) {
  int idx = blockIdx.x * 256 + threadIdx.x;
  const int R = 512 * 192;
  if (idx >= 9 * R) return;
  int tap = idx / R, rr = idx - tap * R;
  int co = rr / 192, ci = rr - co * 192;
  int gate = co >> 7, hch = co & 127;
  int N = ((hch >> 6) << 8) + (((hch & 63) >> 4) << 6) + (gate << 4) + (hch & 15);
  th[(size_t)tap * R + (size_t)N * 192 + ci] = (f16)wsrc[(size_t)rr * 9 + tap];
}

// ---------------- x slice: NCHW fp32 -> padded NHWC f16 ----------------

__global__ __launch_bounds__(256) void kxform(const float* __restrict__ xt,
                                              f16* __restrict__ xp) {
  int pid = blockIdx.x * 256 + threadIdx.x;          // 2*128*128 pixels
  int b = pid >> 14, y = (pid >> 7) & 127, x = pid & 127;
  const float* src = xt + (size_t)b * 64 * 16384 + (size_t)y * 128 + x;
  size_t doff = ((size_t)((b * 130 + y + 1) * 130 + (x + 1))) * 64;
#pragma unroll
  for (int cc = 0; cc < 8; ++cc) {
    f16x8 vh;
#pragma unroll
    for (int j = 0; j < 8; ++j) vh[j] = (f16)src[(size_t)(cc * 8 + j) * 16384];
    *(f16x8*)(xp + doff + cc * 8) = vh;
  }
}

// ---------------- gate conv + fused LSTM ----------------
// implicit GEMM M=32768 N=512 K=1728; block: one y-row (128 px) x 256
// permuted couts (= all 4 gates for 64 hidden ch); 4 waves, wave tile
// 128x64 (acc[8][4], 42.7 FLOP per LDS byte -> LDS-read no longer the cap).
// Counted-vmcnt ring-3 B prefetch (2 taps ahead, steady wait vmcnt(4));
// A patch [3][132][32] halo-reused over 9 taps, restaged per cig (full
// drain only at 6 cig boundaries).  Epilogue: LSTM pointwise in-register
// (nf == gate), reads/writes c (fp32), writes h slice (f16).

#define SMEM_G (25344 + 49152)

__global__ __launch_bounds__(256, 2) void kgates(
    const f16* __restrict__ xp, const f16* __restrict__ hp,
    const f16* __restrict__ wg, const float* __restrict__ bg,
    float* __restrict__ cbuf, f16* __restrict__ hslot) {
  extern __shared__ char smem[];
  f16* Ap = (f16*)smem;                    // [3][132][32]
  f16* Br = (f16*)(smem + 25344);          // ring [3][256][32]
  const int tid = threadIdx.x;
  const int lane = tid & 63;
  const int w = tid >> 6;
  const int y = blockIdx.x;
  const int b = blockIdx.y;
  const int z = blockIdx.z;
  const int n0 = z * 256;
  const int chunk = (lane & 3) ^ ((lane >> 3) & 3);

  f32x4 acc[8][4] = {};

  auto stageA = [&](int cig) {
    const f16* S; int CS, cigl;
    if (cig < 2) { S = xp; CS = 64;  cigl = cig; }
    else         { S = hp; CS = 128; cigl = cig - 2; }
    for (int i = w; i < 27; i += 4) {
      int dy = i / 9, sub = i - dy * 9;
      int xp0 = sub * 16;
      const f16* src = S +
          ((size_t)((b * 130 + y + dy) * 130 + xp0 + (lane >> 2))) * CS +
          cigl * 32 + chunk * 8;
      f16* dst = Ap + (dy * 132 + xp0) * 32;
      if (sub == 8) { if (lane < 16) gld_lds16(dst, src); }
      else gld_lds16(dst, src);
    }
  };
  auto stageB = [&](int cig, int tap, int slot) {   // 4 loads/wave
    f16* dst = Br + slot * 8192;
    for (int i = w; i < 16; i += 4) {
      const f16* src = wg +
          ((size_t)(tap * 512 + n0 + i * 16 + (lane >> 2))) * 192 +
          cig * 32 + chunk * 8;
      gld_lds16(dst + i * 512, src);
    }
  };

  // prologue: A(0) [<=7 loads] + B(0) + B(1) [4 each]; wait A+B0 done
  stageA(0);
  stageB(0, 0, 0);
  stageB(0, 1, 1);
  asm volatile("s_waitcnt vmcnt(4)" ::: "memory");
  __builtin_amdgcn_s_barrier();

  int sl = 0;
  for (int cig = 0; cig < 6; ++cig) {
    for (int tap = 0; tap < 9; ++tap) {
      const int j = cig * 9 + tap;
      const int dy = tap / 3, dx = tap - dy * 3;
      const int q = lane >> 4;
      const f16* Bc = Br + sl * 8192;
      f16x8 af[8], bfr[4];
#pragma unroll
      for (int mf = 0; mf < 8; ++mf) {
        int r = mf * 16 + (lane & 15) + dx;
        af[mf] = *(const f16x8*)(Ap + (dy * 132 + r) * 32 + ((q ^ ((r >> 1) & 3)) << 3));
      }
#pragma unroll
      for (int nf = 0; nf < 4; ++nf) {
        int n = w * 64 + nf * 16 + (lane & 15);
        bfr[nf] = *(const f16x8*)(Bc + n * 32 + ((q ^ ((n >> 1) & 3)) << 3));
      }
      if (j + 2 < 54) {
        int j2 = j + 2;
        stageB(j2 / 9, j2 % 9, (sl + 2 >= 3) ? sl - 1 : sl + 2);
      }
      __builtin_amdgcn_s_setprio(1);
#pragma unroll
      for (int mf = 0; mf < 8; ++mf)
#pragma unroll
        for (int nf = 0; nf < 4; ++nf)
          acc[mf][nf] = __builtin_amdgcn_mfma_f32_16x16x32_f16(af[mf], bfr[nf], acc[mf][nf], 0, 0, 0);
      __builtin_amdgcn_s_setprio(0);
      if (tap == 8) {
        __builtin_amdgcn_s_barrier();        // all waves done reading Ap
        if (cig < 5) stageA(cig + 1);
        asm volatile("s_waitcnt vmcnt(0)" ::: "memory");
        __builtin_amdgcn_s_barrier();
      } else {
        if (j + 2 < 54) asm volatile("s_waitcnt vmcnt(4)" ::: "memory");
        else            asm volatile("s_waitcnt vmcnt(0)" ::: "memory");
        __builtin_amdgcn_s_barrier();
      }
      sl = (sl + 1 >= 3) ? 0 : sl + 1;
    }
  }

  // fused LSTM epilogue: acc[mf][gate][r]; thread owns (px, lch) pairs
  const int lch = w * 16 + (lane & 15);
  const int hch = z * 64 + lch;
  const float bi  = bg[hch];
  const float bf2 = bg[128 + hch];
  const float bo2 = bg[256 + hch];
  const float bg2 = bg[384 + hch];
  const size_t pixbase = ((size_t)(b * 128 + y)) * 128;
  const size_t hbase = ((size_t)((b * 130 + y + 1) * 130 + 1)) * 128 + hch;
#pragma unroll
  for (int mf = 0; mf < 8; ++mf) {
#pragma unroll
    for (int r = 0; r < 4; ++r) {
      int px = mf * 16 + (lane >> 4) * 4 + r;
      size_t cidx = (pixbase + px) * 128 + hch;
      float co = cbuf[cidx];
      float iv = sigf(acc[mf][0][r] + bi);
      float fv = sigf(acc[mf][1][r] + bf2);
      float ov = sigf(acc[mf][2][r] + bo2);
      float gv = tanh_fast(acc[mf][3][r] + bg2);
      float cv = fv * co + iv * gv;
      cbuf[cidx] = cv;
      hslot[hbase + (size_t)px * 128] = (f16)(ov * tanh_fast(cv));
    }
  }
}

// ---------------- output conv, batched over 4 timesteps: M=131072 N=64 K=1152 ----
// block: 128 px row x 64 couts; 4 waves M-split, wave tile 32x64 (acc[2][4]).
// Counted-vmcnt ring-3 pipeline; steady-state wait vmcnt(1).

#define SMEM_O (25344 + 12288)

__global__ __launch_bounds__(256, 4) void koutconv(
    const f16* __restrict__ hr, int slot0, const f16* __restrict__ wo,
    const float* __restrict__ bo, float* __restrict__ outb) {
  extern __shared__ char smem[];
  f16* Ap = (f16*)smem;                    // [3][132][32]
  f16* Br = (f16*)(smem + 25344);          // ring [3][64][32]
  const int tid = threadIdx.x, lane = tid & 63, w = tid >> 6;
  const int y = blockIdx.x;
  const int b = blockIdx.y;
  const int ts = blockIdx.z;
  const f16* hp = hr + (size_t)((slot0 + ts) % 5) * SLICE_H;
  float* outt = outb + (size_t)ts * 2 * 64 * 16384;
  const int chunk = (lane & 3) ^ ((lane >> 3) & 3);

  f32x4 acc[2][4] = {};

  auto stageA = [&](int cig) {
    for (int i = w; i < 27; i += 4) {
      int dy = i / 9, sub = i - dy * 9;
      int xp0 = sub * 16;
      const f16* src = hp +
          ((size_t)((b * 130 + y + dy) * 130 + xp0 + (lane >> 2))) * 128 +
          cig * 32 + chunk * 8;
      f16* dst = Ap + (dy * 132 + xp0) * 32;
      if (sub == 8) { if (lane < 16) gld_lds16(dst, src); }
      else gld_lds16(dst, src);
    }
  };
  auto stageB = [&](int j, int slot) {     // 1 load/wave
    int cig = j / 9, tap = j - cig * 9;
    const f16* src = wo +
        ((size_t)(tap * 64 + w * 16 + (lane >> 2))) * 128 +
        cig * 32 + chunk * 8;
    gld_lds16(Br + slot * 2048 + w * 512, src);
  };

  stageA(0);
  stageB(0, 0);
  stageB(1, 1);
  asm volatile("s_waitcnt vmcnt(1)" ::: "memory");
  __builtin_amdgcn_s_barrier();

  int sl = 0;
  for (int cig = 0; cig < 4; ++cig) {
    for (int tap = 0; tap < 9; ++tap) {
      const int j = cig * 9 + tap;
      const int dy = tap / 3, dx = tap - dy * 3;
      const int q = lane >> 4;
      const f16* Bc = Br + sl * 2048;
      f16x8 af[2], bfr[4];
#pragma unroll
      for (int mf = 0; mf < 2; ++mf) {
        int r = w * 32 + mf * 16 + (lane & 15) + dx;
        af[mf] = *(const f16x8*)(Ap + (dy * 132 + r) * 32 + ((q ^ ((r >> 1) & 3)) << 3));
      }
#pragma unroll
      for (int nf = 0; nf < 4; ++nf) {
        int n = nf * 16 + (lane & 15);
        bfr[nf] = *(const f16x8*)(Bc + n * 32 + ((q ^ ((n >> 1) & 3)) << 3));
      }
      if (j + 2 < 36) stageB(j + 2, (sl + 2 >= 3) ? sl - 1 : sl + 2);
      __builtin_amdgcn_s_setprio(1);
#pragma unroll
      for (int mf = 0; mf < 2; ++mf)
#pragma unroll
        for (int nf = 0; nf < 4; ++nf)
          acc[mf][nf] = __builtin_amdgcn_mfma_f32_16x16x32_f16(af[mf], bfr[nf], acc[mf][nf], 0, 0, 0);
      __builtin_amdgcn_s_setprio(0);
      if (tap == 8) {
        __builtin_amdgcn_s_barrier();
        if (cig < 3) stageA(cig + 1);
        asm volatile("s_waitcnt vmcnt(0)" ::: "memory");
        __builtin_amdgcn_s_barrier();
      } else {
        if (j + 2 < 36) asm volatile("s_waitcnt vmcnt(1)" ::: "memory");
        else            asm volatile("s_waitcnt vmcnt(0)" ::: "memory");
        __builtin_amdgcn_s_barrier();
      }
      sl = (sl + 1 >= 3) ? 0 : sl + 1;
    }
  }

#pragma unroll
  for (int nf = 0; nf < 4; ++nf) {
    int cout = nf * 16 + (lane & 15);
    float bias = bo[cout];
#pragma unroll
    for (int mf = 0; mf < 2; ++mf) {
      int xbase = w * 32 + mf * 16 + (lane >> 4) * 4;
      f32x4 v = acc[mf][nf];
      v[0] += bias; v[1] += bias; v[2] += bias; v[3] += bias;
      *(f32x4*)(outt + (((size_t)b * 64 + cout) * 128 + y) * 128 + xbase) = v;
    }
  }
}

// ---------------- host ----------------

extern "C" void kernel_launch(void* const* d_in, const int* in_sizes, int n_in,
                              void* d_out, int out_size, void* d_ws, size_t ws_size,
                              hipStream_t stream) {
  const float* x  = (const float*)d_in[0];
  const float* Wg = (const float*)d_in[1];
  const float* bg = (const float*)d_in[2];
  const float* Wo = (const float*)d_in[3];
  const float* bo = (const float*)d_in[4];
  float* out = (float*)d_out;

  char* base = (char*)d_ws;
  size_t off = 0;
  auto carve = [&](size_t bytes) {
    char* p = base + off;
    off += (bytes + 1023) & ~(size_t)1023;
    return p;
  };
  const size_t PADPOS = (size_t)2 * 130 * 130;           // 33800 padded positions
  const size_t xpad_b  = PADPOS * 64 * 2 + 1024;          // f16
  const size_t hring_b = (size_t)5 * SLICE_H * 2 + 1024;  // 5 padded h slices, f16
  const size_t c_b = (size_t)2 * 128 * 128 * 128 * 4;     // fp32 cell state

  f16* xp    = (f16*)carve(xpad_b);
  f16* hr    = (f16*)carve(hring_b);
  float* cbuf = (float*)carve(c_b);
  f16* wg    = (f16*)carve((size_t)9 * 512 * 192 * 2);
  f16* wo    = (f16*)carve((size_t)9 * 64 * 128 * 2);

  // zero state + pad borders once (in-stream: graph-replay deterministic;
  // interiors are fully rewritten every use, borders stay zero)
  hipMemsetAsync(xp, 0, xpad_b, stream);
  hipMemsetAsync(hr, 0, hring_b, stream);
  hipMemsetAsync(cbuf, 0, c_b, stream);

  kwtg<<<(9 * 512 * 192 + 255) / 256, 256, 0, stream>>>(Wg, wg);
  kwt<<<(9 * 64 * 128 + 255) / 256, 256, 0, stream>>>(Wo, wo, 64 * 128);

  for (int t = 0; t < 12; ++t) {
    const float* xt = x + (size_t)t * 2 * 64 * 16384;
    kxform<<<128, 256, 0, stream>>>(xt, xp);
    kgates<<<dim3(128, 2, 2), 256, SMEM_G, stream>>>(
        xp, hr + (size_t)(t % 5) * SLICE_H, wg, bg, cbuf,
        hr + (size_t)((t + 1) % 5) * SLICE_H);
    if ((t & 3) == 3) {
      koutconv<<<dim3(128, 2, 4), 256, SMEM_O, stream>>>(
          hr, (t - 2) % 5, wo, bo, out + (size_t)(t - 3) * 2 * 64 * 16384);
    }
  }
}